// Round 1
// baseline (1387.461 us; speedup 1.0000x reference)
//
#include <hip/hip_runtime.h>
#include <math.h>

#define BATCHSZ 128
#define SEQLEN 50
#define DIMSZ 512
#define HIDSZ 2048
#define NVOCAB 32000
#define NROWS (BATCHSZ*SEQLEN)   // 6400

typedef unsigned short u16;
typedef __bf16 bf16x8_t __attribute__((ext_vector_type(8)));
typedef float f32x4_t __attribute__((ext_vector_type(4)));

// float -> bf16 (round to nearest even), avoiding __hip_bfloat16 API entirely
__device__ __forceinline__ u16 f2bf(float f) {
    union { float f; unsigned u; } x; x.f = f;
    return (u16)((x.u + 0x7fffu + ((x.u >> 16) & 1u)) >> 16);
}

// async global->LDS, 16B per lane; LDS dest is wave-uniform base + lane*16
__device__ __forceinline__ void g2l16(const void* g, void* l) {
    __builtin_amdgcn_global_load_lds(
        (const __attribute__((address_space(1))) void*)g,
        (__attribute__((address_space(3))) void*)l, 16, 0, 0);
}

// ---------------------------------------------------------------------------
// W [K,N] f32 (row-major)  ->  WT [N,K] bf16 (row-major). Dims % 32 == 0.
__global__ __launch_bounds__(256)
void transpose_cast_k(const float* __restrict__ W, u16* __restrict__ WT,
                      int K, int N)
{
    __shared__ float tile[32][33];
    const int tx = threadIdx.x & 31;
    const int ty = threadIdx.x >> 5;          // 0..7
    const int nb = blockIdx.x * 32;
    const int kb = blockIdx.y * 32;
    #pragma unroll
    for (int r = ty; r < 32; r += 8)
        tile[r][tx] = W[(size_t)(kb + r) * N + nb + tx];
    __syncthreads();
    #pragma unroll
    for (int r = ty; r < 32; r += 8)
        WT[(size_t)(nb + r) * K + kb + tx] = f2bf(tile[tx][r]);
}

// ---------------------------------------------------------------------------
// x = emb[idx] + pos ; writes f32 and bf16 copies
__global__ __launch_bounds__(256)
void embed_k(const int* __restrict__ idx, const float* __restrict__ emb,
             const float* __restrict__ pos, float* __restrict__ xF,
             u16* __restrict__ xB)
{
    const int row = blockIdx.x;               // b*SEQ + s
    const int s = row % SEQLEN;
    const int t = idx[row];
    const int d = threadIdx.x * 2;
    const float2 e = *(const float2*)(emb + (size_t)t * DIMSZ + d);
    const float2 p = *(const float2*)(pos + (size_t)s * DIMSZ + d);
    float2 v; v.x = e.x + p.x; v.y = e.y + p.y;
    *(float2*)(xF + (size_t)row * DIMSZ + d) = v;
    ushort2 bb; bb.x = f2bf(v.x); bb.y = f2bf(v.y);
    *(ushort2*)(xB + (size_t)row * DIMSZ + d) = bb;
}

// ---------------------------------------------------------------------------
// MFMA bf16 GEMM: C = epi(A[M,K] @ BT[N,K]^T + bias).  M%128==0, N%128==0, K%64==0.
// EPI: 0=none 1=sigmoid 2=gelu(exact).  OUTMODE: 0 -> Cf (f32), 1 -> Cb (bf16)
template<int EPI, int OUTMODE>
__global__ __launch_bounds__(256, 2)
void gemm_bt(const u16* __restrict__ A, const u16* __restrict__ BT,
             const float* __restrict__ bias, float* __restrict__ Cf,
             u16* __restrict__ Cb, int M, int N, int K)
{
    __shared__ __align__(16) u16 As[128 * 64];
    __shared__ __align__(16) u16 Bs[128 * 64];
    const int tid  = threadIdx.x;
    const int wave = tid >> 6;
    const int lane = tid & 63;
    const int quad = lane >> 4;
    const int l16  = lane & 15;
    const int m0 = blockIdx.y * 128;
    const int n0 = blockIdx.x * 128;
    const int wm = (wave >> 1) * 64;          // wave's 64x64 sub-tile
    const int wn = (wave & 1) * 64;

    f32x4_t acc[4][4];
    #pragma unroll
    for (int i = 0; i < 4; ++i)
        #pragma unroll
        for (int j = 0; j < 4; ++j)
            acc[i][j] = (f32x4_t){0.f, 0.f, 0.f, 0.f};

    const int lrow = lane >> 3;               // 0..7 row within 8-row group
    const int lcol = (lane & 7) * 8;          // 0,8,..,56 (elements)

    for (int kt = 0; kt < K; kt += 64) {
        // stage A tile (128x64) and BT tile (128x64); each wave: 4+4 lds-DMA ops
        #pragma unroll
        for (int s = 0; s < 4; ++s) {
            const int rb = wave * 4 + s;      // 8-row block 0..15
            g2l16(A  + (size_t)(m0 + rb * 8 + lrow) * K + kt + lcol, As + rb * 512);
            g2l16(BT + (size_t)(n0 + rb * 8 + lrow) * K + kt + lcol, Bs + rb * 512);
        }
        __syncthreads();                      // drains vmcnt -> LDS valid
        #pragma unroll
        for (int kc = 0; kc < 2; ++kc) {
            bf16x8_t av[4], bv[4];
            #pragma unroll
            for (int i = 0; i < 4; ++i) {
                av[i] = *(const bf16x8_t*)(As + (wm + i * 16 + l16) * 64 + kc * 32 + quad * 8);
                bv[i] = *(const bf16x8_t*)(Bs + (wn + i * 16 + l16) * 64 + kc * 32 + quad * 8);
            }
            #pragma unroll
            for (int i = 0; i < 4; ++i)
                #pragma unroll
                for (int j = 0; j < 4; ++j)
                    acc[i][j] = __builtin_amdgcn_mfma_f32_16x16x32_bf16(
                                    av[i], bv[j], acc[i][j], 0, 0, 0);
        }
        __syncthreads();                      // protect LDS for next stage
    }

    // epilogue: D row = quad*4 + r, col = l16 (verified C/D layout)
    #pragma unroll
    for (int j = 0; j < 4; ++j) {
        const int col = n0 + wn + j * 16 + l16;
        const float bc = bias[col];
        #pragma unroll
        for (int i = 0; i < 4; ++i) {
            const int rbase = m0 + wm + i * 16 + quad * 4;
            #pragma unroll
            for (int r = 0; r < 4; ++r) {
                float v = acc[i][j][r] + bc;
                if (EPI == 1) v = 1.0f / (1.0f + expf(-v));
                if (EPI == 2) v = 0.5f * v * (1.0f + erff(v * 0.70710678118654752f));
                const size_t o = (size_t)(rbase + r) * N + col;
                if (OUTMODE == 0) Cf[o] = v;
                else              Cb[o] = f2bf(v);
            }
        }
    }
}

// ---------------------------------------------------------------------------
// Fused Lukasiewicz attention: one block per (b,i) row.
// logit[j] = (j<=i) ? 10*(1 - mean_d relu(Q_i - K_j)) : 0 ; softmax over ALL j
__global__ __launch_bounds__(256)
void attn_k(const float* __restrict__ Q, const float* __restrict__ Kmat,
            const float* __restrict__ V, float* __restrict__ out)
{
    const int row = blockIdx.x;               // b*SEQ + i
    const int b = row / SEQLEN;
    const int i = row - b * SEQLEN;
    const int tid = threadIdx.x;
    const int wave = tid >> 6, lane = tid & 63;
    __shared__ float logits[64];
    __shared__ float attnw[64];
    if (tid < 64) logits[tid] = 0.0f;         // masked (j>i) keep logit 0
    __syncthreads();

    const float* qrow = Q + (size_t)row * DIMSZ;
    const float4 q0 = *(const float4*)(qrow + lane * 8);
    const float4 q1 = *(const float4*)(qrow + lane * 8 + 4);
    const float* kbase = Kmat + (size_t)b * SEQLEN * DIMSZ;
    for (int j = wave; j <= i; j += 4) {
        const float* kr = kbase + (size_t)j * DIMSZ;
        const float4 k0 = *(const float4*)(kr + lane * 8);
        const float4 k1 = *(const float4*)(kr + lane * 8 + 4);
        float s = fmaxf(q0.x - k0.x, 0.f) + fmaxf(q0.y - k0.y, 0.f)
                + fmaxf(q0.z - k0.z, 0.f) + fmaxf(q0.w - k0.w, 0.f)
                + fmaxf(q1.x - k1.x, 0.f) + fmaxf(q1.y - k1.y, 0.f)
                + fmaxf(q1.z - k1.z, 0.f) + fmaxf(q1.w - k1.w, 0.f);
        #pragma unroll
        for (int off = 32; off; off >>= 1) s += __shfl_xor(s, off);
        if (lane == 0) logits[j] = 10.0f * (1.0f - s * (1.0f / DIMSZ));
    }
    __syncthreads();

    if (tid < 64) {                           // wave 0 does the 50-wide softmax
        const float t = (tid < SEQLEN) ? logits[tid] : -1e30f;
        float m = t;
        #pragma unroll
        for (int off = 32; off; off >>= 1) m = fmaxf(m, __shfl_xor(m, off));
        const float e = (tid < SEQLEN) ? expf(t - m) : 0.0f;
        float ss = e;
        #pragma unroll
        for (int off = 32; off; off >>= 1) ss += __shfl_xor(ss, off);
        attnw[tid] = e / ss;
    }
    __syncthreads();

    const int d = tid * 2;
    const float* vbase = V + (size_t)b * SEQLEN * DIMSZ + d;
    float2 a; a.x = 0.f; a.y = 0.f;
    for (int j = 0; j < SEQLEN; ++j) {
        const float w = attnw[j];
        const float2 vv = *(const float2*)(vbase + (size_t)j * DIMSZ);
        a.x += w * vv.x; a.y += w * vv.y;
    }
    *(float2*)(out + (size_t)row * DIMSZ + d) = a;
}

// ---------------------------------------------------------------------------
// out = LN(X + Y; g, be) ; writes f32 and bf16
__global__ __launch_bounds__(256)
void resid_ln_k(const float* __restrict__ X, const float* __restrict__ Y,
                const float* __restrict__ g, const float* __restrict__ be,
                float* __restrict__ outF, u16* __restrict__ outB)
{
    const int row = blockIdx.x;
    const int tid = threadIdx.x;
    const int d = tid * 2;
    const float2 a = *(const float2*)(X + (size_t)row * DIMSZ + d);
    const float2 bvv = *(const float2*)(Y + (size_t)row * DIMSZ + d);
    float2 v; v.x = a.x + bvv.x; v.y = a.y + bvv.y;
    float s = v.x + v.y, s2 = v.x * v.x + v.y * v.y;
    #pragma unroll
    for (int off = 32; off; off >>= 1) { s += __shfl_xor(s, off); s2 += __shfl_xor(s2, off); }
    __shared__ float red[8];
    const int wave = tid >> 6, lane = tid & 63;
    if (lane == 0) { red[wave] = s; red[4 + wave] = s2; }
    __syncthreads();
    s  = red[0] + red[1] + red[2] + red[3];
    s2 = red[4] + red[5] + red[6] + red[7];
    const float mean = s * (1.0f / DIMSZ);
    const float var  = s2 * (1.0f / DIMSZ) - mean * mean;
    const float rstd = rsqrtf(var + 1e-5f);
    const float2 gg = *(const float2*)(g + d);
    const float2 bb = *(const float2*)(be + d);
    float2 o;
    o.x = (v.x - mean) * rstd * gg.x + bb.x;
    o.y = (v.y - mean) * rstd * gg.y + bb.y;
    *(float2*)(outF + (size_t)row * DIMSZ + d) = o;
    ushort2 ob; ob.x = f2bf(o.x); ob.y = f2bf(o.y);
    *(ushort2*)(outB + (size_t)row * DIMSZ + d) = ob;
}

// ---------------------------------------------------------------------------
extern "C" void kernel_launch(void* const* d_in, const int* in_sizes, int n_in,
                              void* d_out, int out_size, void* d_ws, size_t ws_size,
                              hipStream_t stream)
{
    const int*   idx = (const int*)  d_in[0];
    const float* emb = (const float*)d_in[1];
    const float* pos = (const float*)d_in[2];
    const float* wq  = (const float*)d_in[3];
    const float* bq  = (const float*)d_in[4];
    const float* wk  = (const float*)d_in[5];
    const float* bk  = (const float*)d_in[6];
    const float* wv  = (const float*)d_in[7];
    const float* bv  = (const float*)d_in[8];
    const float* w1  = (const float*)d_in[9];
    const float* b1  = (const float*)d_in[10];
    const float* w2  = (const float*)d_in[11];
    const float* b2  = (const float*)d_in[12];
    const float* g1  = (const float*)d_in[13];
    const float* be1 = (const float*)d_in[14];
    const float* g2  = (const float*)d_in[15];
    const float* be2 = (const float*)d_in[16];
    const float* wo  = (const float*)d_in[17];
    const float* bo  = (const float*)d_in[18];
    float* outp = (float*)d_out;
    char* ws = (char*)d_ws;

    // workspace layout (bytes); total requirement ~136.9 MB
    float* x_f32  = (float*)(ws + 0);           // 13107200
    float* x1_f32 = (float*)(ws + 13107200);    // 13107200
    u16*   x_bf   = (u16*)  (ws + 26214400);    //  6553600
    u16*   x1_bf  = (u16*)  (ws + 32768000);    //  6553600
    u16*   x2_bf  = (u16*)  (ws + 39321600);    //  6553600
    float* Qb     = (float*)(ws + 45875200);    // 13107200
    float* Kb     = (float*)(ws + 58982400);    // 13107200
    float* Vb     = (float*)(ws + 72089600);    // 13107200
    float* ao     = (float*)(ws + 85196800);    // 13107200
    u16*   h_bf   = (u16*)  (ws + 45875200);    // 26214400 (overlays Q,K — dead)
    float* f_f32  = (float*)(ws + 72089600);    // 13107200 (overlays V — dead)
    u16*   wqT    = (u16*)  (ws + 98304000);    //   524288
    u16*   wkT    = (u16*)  (ws + 98828288);
    u16*   wvT    = (u16*)  (ws + 99352576);
    u16*   w1T    = (u16*)  (ws + 99876864);    //  2097152
    u16*   w2T    = (u16*)  (ws + 101974016);   //  2097152
    u16*   woT    = (u16*)  (ws + 104071168);   // 32768000 -> end 136839168

    // weight transpose + bf16 cast
    transpose_cast_k<<<dim3(DIMSZ/32,  DIMSZ/32), 256, 0, stream>>>(wq, wqT, DIMSZ, DIMSZ);
    transpose_cast_k<<<dim3(DIMSZ/32,  DIMSZ/32), 256, 0, stream>>>(wk, wkT, DIMSZ, DIMSZ);
    transpose_cast_k<<<dim3(DIMSZ/32,  DIMSZ/32), 256, 0, stream>>>(wv, wvT, DIMSZ, DIMSZ);
    transpose_cast_k<<<dim3(HIDSZ/32,  DIMSZ/32), 256, 0, stream>>>(w1, w1T, DIMSZ, HIDSZ);
    transpose_cast_k<<<dim3(DIMSZ/32,  HIDSZ/32), 256, 0, stream>>>(w2, w2T, HIDSZ, DIMSZ);
    transpose_cast_k<<<dim3(NVOCAB/32, DIMSZ/32), 256, 0, stream>>>(wo, woT, DIMSZ, NVOCAB);

    embed_k<<<NROWS, 256, 0, stream>>>(idx, emb, pos, x_f32, x_bf);

    gemm_bt<1,0><<<dim3(DIMSZ/128, NROWS/128), 256, 0, stream>>>(x_bf, wqT, bq, Qb, nullptr, NROWS, DIMSZ, DIMSZ);
    gemm_bt<1,0><<<dim3(DIMSZ/128, NROWS/128), 256, 0, stream>>>(x_bf, wkT, bk, Kb, nullptr, NROWS, DIMSZ, DIMSZ);
    gemm_bt<0,0><<<dim3(DIMSZ/128, NROWS/128), 256, 0, stream>>>(x_bf, wvT, bv, Vb, nullptr, NROWS, DIMSZ, DIMSZ);

    attn_k<<<NROWS, 256, 0, stream>>>(Qb, Kb, Vb, ao);

    resid_ln_k<<<NROWS, 256, 0, stream>>>(x_f32, ao, g1, be1, x1_f32, x1_bf);

    gemm_bt<2,1><<<dim3(HIDSZ/128, NROWS/128), 256, 0, stream>>>(x1_bf, w1T, b1, nullptr, h_bf, NROWS, HIDSZ, DIMSZ);
    gemm_bt<0,0><<<dim3(DIMSZ/128, NROWS/128), 256, 0, stream>>>(h_bf, w2T, b2, f_f32, nullptr, NROWS, DIMSZ, HIDSZ);

    resid_ln_k<<<NROWS, 256, 0, stream>>>(x1_f32, f_f32, g2, be2, x_f32, x2_bf);

    gemm_bt<0,0><<<dim3(NVOCAB/128, NROWS/128), 256, 0, stream>>>(x2_bf, woT, bo, outp, nullptr, NROWS, NVOCAB, DIMSZ);
}